// Round 2
// baseline (205128.320 us; speedup 1.0000x reference)
//
#include <hip/hip_runtime.h>

// NDDE forward-Euler, d=512, N=2000 sequential steps — latency-bound on the
// cross-WG x-exchange. R2: elect 32 WGs on ONE XCD (HW_REG_XCC_ID + device
// atomics); exchange through the shared per-XCD L2 (plain stores + sc0-only
// loads, ~200cyc RTT) instead of the MALL (~1-2us RTT). Escalation to
// agent-scope polls (R1-proven) if the fast path ever stalls.

#define D       512
#define NTAU    100
#define M       112   // ring columns, > delay span 102; mod kept incrementally
#define NT      256
#define NLAUNCH 512   // launched WGs; 32 elected, rest exit
#define NWORK   32
#define FASTTRIES 512

typedef unsigned long long u64;

__device__ __forceinline__ float lo_f(u64 v){ union{unsigned u; float f;} c; c.u=(unsigned)v; return c.f; }
__device__ __forceinline__ u64 pack_rec(unsigned tag, float x){ union{unsigned u; float f;} c; c.f=x; return ((u64)tag<<32)|(u64)c.u; }

// L1-bypassing, L2-served loads (sc0 only — NOT sc1, stay in the XCD L2)
__device__ __forceinline__ void poll2_sc0(const u64* p0, const u64* p1, u64& a, u64& b){
    asm volatile("global_load_dwordx2 %0, %2, off sc0\n\t"
                 "global_load_dwordx2 %1, %3, off sc0\n\t"
                 "s_waitcnt vmcnt(0)"
                 : "=&v"(a), "=&v"(b) : "v"(p0), "v"(p1));
}
__device__ __forceinline__ void poll4_sc0(const u64* p0, const u64* p1,
                                          const u64* p2, const u64* p3,
                                          u64& a, u64& b, u64& c, u64& d){
    asm volatile("global_load_dwordx2 %0, %4, off sc0\n\t"
                 "global_load_dwordx2 %1, %5, off sc0\n\t"
                 "global_load_dwordx2 %2, %6, off sc0\n\t"
                 "global_load_dwordx2 %3, %7, off sc0\n\t"
                 "s_waitcnt vmcnt(0)"
                 : "=&v"(a), "=&v"(b), "=&v"(c), "=&v"(d)
                 : "v"(p0), "v"(p1), "v"(p2), "v"(p3));
}

__global__ __launch_bounds__(NT, 1) void ndde_xcd(
    const float* __restrict__ x0p, const float* __restrict__ taup,
    const float* __restrict__ W1,  const float* __restrict__ W2,
    const float* __restrict__ bb,  const int* __restrict__ Np,
    float* __restrict__ out, int* __restrict__ ectl, u64* __restrict__ ring)
{
    const int tid = threadIdx.x;
    __shared__ int s_rank;
    __shared__ __align__(16) float vsh[2][1032];   // [x 512 | y 512 | pad]

    // ---- same-XCD election: first XCD to seat 32 WGs wins ----
    int xcd;
    asm("s_getreg_b32 %0, hwreg(HW_REG_XCC_ID, 0, 4)" : "=s"(xcd));
    xcd &= 7;
    if (tid == 0){
        int r = __hip_atomic_fetch_add(&ectl[8 + xcd], 1, __ATOMIC_RELAXED, __HIP_MEMORY_SCOPE_AGENT);
        int part = -1;
        if (r < NWORK){
            if (r == NWORK - 1){
                int expv = 0;
                __hip_atomic_compare_exchange_strong(&ectl[0], &expv, xcd + 1,
                    __ATOMIC_RELAXED, __ATOMIC_RELAXED, __HIP_MEMORY_SCOPE_AGENT);
            }
            int w, g = 1 << 24;
            do { w = __hip_atomic_load(&ectl[0], __ATOMIC_RELAXED, __HIP_MEMORY_SCOPE_AGENT); }
            while (w == 0 && --g);
            if (w == xcd + 1) part = r;
        }
        s_rank = part;
    }
    __syncthreads();
    const int rank = s_rank;
    if (rank < 0) return;          // not elected

    const int   N  = Np[0];
    const float dt = 0.01f * taup[0];
    const int lane = tid & 63;
    const int wv   = tid >> 6;
    const int r4   = lane >> 4;    // row within wave's 4
    const int q    = lane & 15;    // 32-col chunk within row
    const int row  = rank * 16 + wv * 4 + r4;

    // ---- weights -> VGPRs (rotated chunk order breaks LDS bank collisions) ----
    const float4* w1row = (const float4*)(W1 + (size_t)row * D);
    const float4* w2row = (const float4*)(W2 + (size_t)row * D);
    float4 w1[8], w2[8];
    int cidx[8];
    #pragma unroll
    for (int i = 0; i < 8; ++i){
        const int c = 8 * q + ((q + i) & 7);   // float4 index 0..127
        cidx[i] = c;
        w1[i] = w1row[c];
        w2[i] = w2row[c];
    }

    // ---- integrator state in q==0 lanes; publish x0 (tag = step+1 = 1) ----
    float xloc = 0.f, bval = 0.f;
    if (q == 0){
        xloc = x0p[row];
        bval = bb[row];
        out[(size_t)row * (N + 1)] = xloc;
        *(volatile u64*)(ring + row) = pack_rec(1u, xloc);
    }

    u64 vx0, vx1, vy0 = 0, vy1 = 0;
    bool dead = false;
    int sx = 0, sy = 0, sp = 1;    // j%M, jy%M, (j+1)%M — incremental

    for (int j = 0; j < N && !dead; ++j){
        const int jy = (j > NTAU) ? (j - NTAU) : 0;
        const bool needy = (j < 2) || (j > NTAU);
        const unsigned tx = (unsigned)(j + 1), ty = (unsigned)(jy + 1);
        const u64* px = ring + (size_t)sx * D;
        const u64* py = ring + (size_t)sy * D;
        const u64 *px0 = px + tid, *px1 = px + tid + 256;
        const u64 *py0 = py + tid, *py1 = py + tid + 256;

        // ---- spin for x_j (and y when needed) in the shared XCD L2 ----
        int tries = 0;
        for (;;){
            if (tries < FASTTRIES){
                if (needy) poll4_sc0(px0, px1, py0, py1, vx0, vx1, vy0, vy1);
                else       poll2_sc0(px0, px1, vx0, vx1);
            } else {     // escalation: agent scope (MALL) — R1-proven path
                vx0 = __hip_atomic_load(px0, __ATOMIC_RELAXED, __HIP_MEMORY_SCOPE_AGENT);
                vx1 = __hip_atomic_load(px1, __ATOMIC_RELAXED, __HIP_MEMORY_SCOPE_AGENT);
                if (needy){
                    vy0 = __hip_atomic_load(py0, __ATOMIC_RELAXED, __HIP_MEMORY_SCOPE_AGENT);
                    vy1 = __hip_atomic_load(py1, __ATOMIC_RELAXED, __HIP_MEMORY_SCOPE_AGENT);
                }
            }
            bool ok = ((unsigned)(vx0 >> 32) == tx) && ((unsigned)(vx1 >> 32) == tx);
            if (needy) ok = ok && ((unsigned)(vy0 >> 32) == ty) && ((unsigned)(vy1 >> 32) == ty);
            if (__all(ok)) break;
            if (++tries > (1 << 18)){ dead = true; break; }
        }

        // ---- broadcast through LDS (parity double-buffer) ----
        float* v = vsh[j & 1];
        v[tid]       = lo_f(vx0);
        v[tid + 256] = lo_f(vx1);
        if (needy){
            v[512 + tid]       = lo_f(vy0);
            v[512 + tid + 256] = lo_f(vy1);
        }
        __syncthreads();

        // ---- 32 cols of W1 + 32 cols of W2 per lane; 4 FMA chains ----
        const float4* vx4 = (const float4*)v;
        const float4* vy4 = (const float4*)(v + 512);
        float a0 = 0.f, a1 = 0.f, a2 = 0.f, a3 = 0.f;
        #pragma unroll
        for (int i = 0; i < 8; i += 2){
            const int c0 = cidx[i], c1 = cidx[i + 1];
            const float4 xa = vx4[c0], ya = vy4[c0];
            const float4 xb = vx4[c1], yb = vy4[c1];
            a0 = fmaf(w1[i].x, xa.x, a0);   a0 = fmaf(w1[i].y, xa.y, a0);
            a0 = fmaf(w1[i].z, xa.z, a0);   a0 = fmaf(w1[i].w, xa.w, a0);
            a1 = fmaf(w2[i].x, ya.x, a1);   a1 = fmaf(w2[i].y, ya.y, a1);
            a1 = fmaf(w2[i].z, ya.z, a1);   a1 = fmaf(w2[i].w, ya.w, a1);
            a2 = fmaf(w1[i+1].x, xb.x, a2); a2 = fmaf(w1[i+1].y, xb.y, a2);
            a2 = fmaf(w1[i+1].z, xb.z, a2); a2 = fmaf(w1[i+1].w, xb.w, a2);
            a3 = fmaf(w2[i+1].x, yb.x, a3); a3 = fmaf(w2[i+1].y, yb.y, a3);
            a3 = fmaf(w2[i+1].z, yb.z, a3); a3 = fmaf(w2[i+1].w, yb.w, a3);
        }
        float acc = (a0 + a1) + (a2 + a3);

        // ---- 4-level butterfly over the 16 q-lanes ----
        acc += __shfl_xor(acc, 8, 16);
        acc += __shfl_xor(acc, 4, 16);
        acc += __shfl_xor(acc, 2, 16);
        acc += __shfl_xor(acc, 1, 16);

        // ---- integrate; publish record first (it's the critical path) ----
        if (q == 0){
            const float xn = xloc + dt * tanhf(acc + bval);
            xloc = xn;
            *(volatile u64*)(ring + (size_t)sp * D + row) = pack_rec(tx + 1, xn);
            out[(size_t)row * (N + 1) + (j + 1)] = xn;
        }

        sx = (sx == M - 1) ? 0 : sx + 1;
        sp = (sp == M - 1) ? 0 : sp + 1;
        if (j >= NTAU) sy = (sy == M - 1) ? 0 : sy + 1;
    }
}

extern "C" void kernel_launch(void* const* d_in, const int* in_sizes, int n_in,
                              void* d_out, int out_size, void* d_ws, size_t ws_size,
                              hipStream_t stream)
{
    const float* x0  = (const float*)d_in[0];
    const float* tau = (const float*)d_in[1];
    const float* W1  = (const float*)d_in[2];
    const float* W2  = (const float*)d_in[3];
    const float* b   = (const float*)d_in[4];
    const int*   Np  = (const int*)  d_in[5];

    // d_ws layout: [0,4096) election (zeroed); [4096, 4096+M*512*8) ring.
    // Total 452 KB — fits the >=512 KB proven available in R1.
    hipMemsetAsync(d_ws, 0, 4096, stream);
    int* ectl = (int*)d_ws;
    u64* ring = (u64*)((char*)d_ws + 4096);

    hipLaunchKernelGGL(ndde_xcd, dim3(NLAUNCH), dim3(NT), 0, stream,
                       x0, tau, W1, W2, b, Np, (float*)d_out, ectl, ring);
}

// Round 4
// 3627.360 us; speedup vs baseline: 56.5503x; 56.5503x over previous
//
#include <hip/hip_runtime.h>

// NDDE forward-Euler, d=512, N=2000 sequential steps. Latency-bound on the
// per-step all-to-all of the 512-vector x_j. R4: trimmed agent-scope design.
//   - 128 WGs x 64 threads; each WAVE owns 4 rows; no LDS, no syncthreads.
//   - Exchange: ring of tagged 8B records {step-tag, fp32}, agent-scope
//     atomics only (R1-proven coherent channel; R2 proved hand-rolled sc0
//     asm reads stale L1).
//   - Record->lane map 64*i+lane: every poll load is a contiguous 512B
//     wave access (coalesced at the MALL).
//   - y (100 steps stale) loads issued BEFORE the x-spin, tag-verified
//     after; W2*x0 partial cached for j<=100; step 0 computed locally.
//   - Weights pinned in VGPRs with empty-asm "+v" pins (R1 VGPR=56 showed
//     the compiler re-fetching them every step).

#define D    512
#define NTAU 100
#define M    112          // ring depth > delay span 101 + skew
#define NWGS 128          // 128 waves of 64; wave w owns rows 4w..4w+3

typedef unsigned long long u64;

__device__ __forceinline__ float lo_f(u64 v){ union{unsigned u; float f;} c; c.u=(unsigned)v; return c.f; }
__device__ __forceinline__ u64 pack_rec(unsigned tag, float x){ union{unsigned u; float f;} c; c.f=x; return ((u64)tag<<32)|(u64)c.u; }
__device__ __forceinline__ u64 ag_ld(const u64* p){
    return __hip_atomic_load(p, __ATOMIC_RELAXED, __HIP_MEMORY_SCOPE_AGENT);
}
__device__ __forceinline__ void ag_st(u64* p, u64 v){
    __hip_atomic_store(p, v, __ATOMIC_RELAXED, __HIP_MEMORY_SCOPE_AGENT);
}

__global__ __launch_bounds__(64, 1) void ndde_r4(
    const float* __restrict__ x0p, const float* __restrict__ taup,
    const float* __restrict__ W1,  const float* __restrict__ W2,
    const float* __restrict__ bb,  const int* __restrict__ Np,
    float* __restrict__ out, u64* __restrict__ ring)
{
    const int lane    = threadIdx.x & 63;
    const int rowbase = blockIdx.x * 4;
    const int N       = Np[0];
    const float dt    = 0.01f * taup[0];

    // ---- weights: 4 rows x 8 strided cols (col = 64*i + lane) ----
    float w1v[4][8], w2v[4][8];
    #pragma unroll
    for (int r = 0; r < 4; ++r){
        const float* p1 = W1 + (size_t)(rowbase + r) * D + lane;
        const float* p2 = W2 + (size_t)(rowbase + r) * D + lane;
        #pragma unroll
        for (int i = 0; i < 8; ++i){
            w1v[r][i] = p1[64 * i];
            w2v[r][i] = p2[64 * i];
        }
    }
    // pin weights in VGPRs: opaque empty asm prevents remat/sinking
    #pragma unroll
    for (int r = 0; r < 4; ++r){
        #pragma unroll
        for (int i = 0; i < 8; ++i)
            asm volatile("" : "+v"(w1v[r][i]), "+v"(w2v[r][i]));
    }

    // ---- x0 partials: t = W1*x0, yp = W2*x0 (yp reused for all j <= 100) ----
    float xv0[8];
    #pragma unroll
    for (int i = 0; i < 8; ++i) xv0[i] = x0p[64 * i + lane];
    float yp[4], a0, a1, a2, a3;
    {
        float t[4];
        #pragma unroll
        for (int r = 0; r < 4; ++r){
            float sy = 0.f, st = 0.f;
            #pragma unroll
            for (int i = 0; i < 8; ++i){
                sy = fmaf(w2v[r][i], xv0[i], sy);
                st = fmaf(w1v[r][i], xv0[i], st);
            }
            yp[r] = sy; t[r] = st;
        }
        a0 = t[0] + yp[0]; a1 = t[1] + yp[1];
        a2 = t[2] + yp[2]; a3 = t[3] + yp[3];
    }
    #pragma unroll
    for (int off = 32; off >= 1; off >>= 1){
        a0 += __shfl_xor(a0, off, 64);
        a1 += __shfl_xor(a1, off, 64);
        a2 += __shfl_xor(a2, off, 64);
        a3 += __shfl_xor(a3, off, 64);
    }

    // ---- step 0 local; publish x_1 (tag 2) into slot 1 ----
    float xloc = 0.f, bval = 0.f;
    if (lane < 4){
        const int row = rowbase + lane;
        xloc = x0p[row];
        bval = bb[row];
        out[(size_t)row * (N + 1)] = xloc;
        if (N >= 1){
            const float acc = (lane == 0) ? a0 : (lane == 1) ? a1
                            : (lane == 2) ? a2 : a3;
            const float x1 = xloc + dt * tanhf(acc + bval);
            xloc = x1;
            ag_st(ring + D + row, pack_rec(2u, x1));
            out[(size_t)row * (N + 1) + 1] = x1;
        }
    }

    // ---- main loop: j = 1 .. N-1 ----
    u64 xr[8], yr[8];
    int sx = 1, sp = 2, sy = 1;          // j%M, (j+1)%M, (j-100)%M
    bool dead = false;

    for (int j = 1; j < N && !dead; ++j){
        const bool needy  = (j > NTAU);
        const unsigned tx = (unsigned)(j + 1);
        const u64* px = ring + (size_t)sx * D + lane;

        // y loads first: 100 steps stale, they drain in the x-spin's shadow
        if (needy){
            const u64* py = ring + (size_t)sy * D + lane;
            #pragma unroll
            for (int i = 0; i < 8; ++i) yr[i] = ag_ld(py + 64 * i);
        }

        // ---- spin for x_j: 8 coalesced agent dwordx2 per lane ----
        int it = 0;
        for (;;){
            #pragma unroll
            for (int i = 0; i < 8; ++i) xr[i] = ag_ld(px + 64 * i);
            bool ok = true;
            #pragma unroll
            for (int i = 0; i < 8; ++i) ok &= ((unsigned)(xr[i] >> 32) == tx);
            if (__all(ok)) break;
            if (++it > (1 << 22)){ dead = true; break; }
        }

        // ---- y tag verify (stale is rare; bounded re-spin) ----
        if (needy){
            const unsigned ty = (unsigned)(j - NTAU + 1);
            bool ok = true;
            #pragma unroll
            for (int i = 0; i < 8; ++i) ok &= ((unsigned)(yr[i] >> 32) == ty);
            if (!__all(ok)){
                const u64* py = ring + (size_t)sy * D + lane;
                int it2 = 0;
                for (;;){
                    #pragma unroll
                    for (int i = 0; i < 8; ++i) yr[i] = ag_ld(py + 64 * i);
                    bool ok2 = true;
                    #pragma unroll
                    for (int i = 0; i < 8; ++i) ok2 &= ((unsigned)(yr[i] >> 32) == ty);
                    if (__all(ok2)) break;
                    if (++it2 > (1 << 22)){ dead = true; break; }
                }
            }
        }

        // ---- 64 FMAs: 4 rows x 8 cols x (W1,W2) ----
        if (needy){
            a0 = a1 = a2 = a3 = 0.f;
            #pragma unroll
            for (int i = 0; i < 8; ++i){
                const float xf = lo_f(xr[i]), yf = lo_f(yr[i]);
                a0 = fmaf(w1v[0][i], xf, a0); a0 = fmaf(w2v[0][i], yf, a0);
                a1 = fmaf(w1v[1][i], xf, a1); a1 = fmaf(w2v[1][i], yf, a1);
                a2 = fmaf(w1v[2][i], xf, a2); a2 = fmaf(w2v[2][i], yf, a2);
                a3 = fmaf(w1v[3][i], xf, a3); a3 = fmaf(w2v[3][i], yf, a3);
            }
        } else {
            a0 = yp[0]; a1 = yp[1]; a2 = yp[2]; a3 = yp[3];
            #pragma unroll
            for (int i = 0; i < 8; ++i){
                const float xf = lo_f(xr[i]);
                a0 = fmaf(w1v[0][i], xf, a0);
                a1 = fmaf(w1v[1][i], xf, a1);
                a2 = fmaf(w1v[2][i], xf, a2);
                a3 = fmaf(w1v[3][i], xf, a3);
            }
        }

        // ---- butterfly: all lanes end with all 4 row sums ----
        #pragma unroll
        for (int off = 32; off >= 1; off >>= 1){
            a0 += __shfl_xor(a0, off, 64);
            a1 += __shfl_xor(a1, off, 64);
            a2 += __shfl_xor(a2, off, 64);
            a3 += __shfl_xor(a3, off, 64);
        }

        // ---- integrate; ring publish first (critical path), then out ----
        if (lane < 4){
            const float acc = (lane == 0) ? a0 : (lane == 1) ? a1
                            : (lane == 2) ? a2 : a3;
            const float xn = xloc + dt * tanhf(acc + bval);
            xloc = xn;
            const int row = rowbase + lane;
            ag_st(ring + (size_t)sp * D + row, pack_rec(tx + 1, xn));
            out[(size_t)row * (N + 1) + (j + 1)] = xn;
        }

        sx = (sx == M - 1) ? 0 : sx + 1;
        sp = (sp == M - 1) ? 0 : sp + 1;
        if (j >= NTAU + 1) sy = (sy == M - 1) ? 0 : sy + 1;
    }
}

extern "C" void kernel_launch(void* const* d_in, const int* in_sizes, int n_in,
                              void* d_out, int out_size, void* d_ws, size_t ws_size,
                              hipStream_t stream)
{
    const float* x0  = (const float*)d_in[0];
    const float* tau = (const float*)d_in[1];
    const float* W1  = (const float*)d_in[2];
    const float* W2  = (const float*)d_in[3];
    const float* b   = (const float*)d_in[4];
    const int*   Np  = (const int*)  d_in[5];

    // ring: M*512*8 = 448 KB in d_ws. No memset needed: tags are 1..N+1 and
    // the 0xAA poison word never matches a valid tag.
    u64* ring = (u64*)d_ws;

    hipLaunchKernelGGL(ndde_r4, dim3(NWGS), dim3(64), 0, stream,
                       x0, tau, W1, W2, b, Np, (float*)d_out, ring);
}

// Round 5
// 2960.667 us; speedup vs baseline: 69.2845x; 1.2252x over previous
//
#include <hip/hip_runtime.h>

// NDDE forward-Euler, d=512, N=2000 — latency-bound on the per-step
// all-to-all exchange through the MALL (agent scope, R1/R4-proven).
// R5: contention/tail reduction.
//   - 64 waves (64 WGs x 64 thr), each owns 8 rows; weights 128 VGPR/thread.
//   - y (= x_{j-100}) never touches the MALL: wave-private fp32 history in
//     d_ws written/read with PLAIN stores/loads (same wave wrote it -> same
//     CU L1, trivially coherent). y-partial computed in the post-publish
//     shadow for the next step. Fallback to R4 agent-y if ws too small.
//   - x exchange unchanged: tagged u64 records, agent atomics, 8 coalesced
//     polls/lane, publish-before-out.

#define D     512
#define NTAU  100
#define M     112        // ring depth > delay span 101 + skew
#define HSLOT 101        // private history depth
#define NW    64         // waves; wave w owns rows 8w..8w+7

typedef unsigned long long u64;

__device__ __forceinline__ float lo_f(u64 v){ union{unsigned u; float f;} c; c.u=(unsigned)v; return c.f; }
__device__ __forceinline__ u64 pack_rec(unsigned tag, float x){ union{unsigned u; float f;} c; c.f=x; return ((u64)tag<<32)|(u64)c.u; }
__device__ __forceinline__ u64 ag_ld(const u64* p){
    return __hip_atomic_load(p, __ATOMIC_RELAXED, __HIP_MEMORY_SCOPE_AGENT);
}
__device__ __forceinline__ void ag_st(u64* p, u64 v){
    __hip_atomic_store(p, v, __ATOMIC_RELAXED, __HIP_MEMORY_SCOPE_AGENT);
}
// 8-way select a[k] without dynamic indexing (7 cndmask)
__device__ __forceinline__ float sel8(const float* a, int k){
    float s = a[0];
    s = (k == 1) ? a[1] : s;  s = (k == 2) ? a[2] : s;
    s = (k == 3) ? a[3] : s;  s = (k == 4) ? a[4] : s;
    s = (k == 5) ? a[5] : s;  s = (k == 6) ? a[6] : s;
    s = (k == 7) ? a[7] : s;
    return s;
}

__global__ __launch_bounds__(64, 1) void ndde_r5(
    const float* __restrict__ x0p, const float* __restrict__ taup,
    const float* __restrict__ W1,  const float* __restrict__ W2,
    const float* __restrict__ bb,  const int* __restrict__ Np,
    float* __restrict__ out, u64* __restrict__ ring,
    float* __restrict__ hist, int use_hist)
{
    const int lane    = threadIdx.x & 63;
    const int wb      = blockIdx.x;          // 0..63
    const int rowbase = wb * 8;
    const int N       = Np[0];
    const float dt    = 0.01f * taup[0];

    // ---- weights: 8 rows x 8 strided cols (col = 64*i + lane) ----
    float w1v[8][8], w2v[8][8];
    #pragma unroll
    for (int r = 0; r < 8; ++r){
        const float* p1 = W1 + (size_t)(rowbase + r) * D + lane;
        const float* p2 = W2 + (size_t)(rowbase + r) * D + lane;
        #pragma unroll
        for (int i = 0; i < 8; ++i){
            w1v[r][i] = p1[64 * i];
            w2v[r][i] = p2[64 * i];
        }
    }
    #pragma unroll
    for (int r = 0; r < 8; ++r){
        #pragma unroll
        for (int i = 0; i < 8; ++i)
            asm volatile("" : "+v"(w1v[r][i]), "+v"(w2v[r][i]));
    }

    // ---- x0 partials: yp = W2*x0 (reused for all j <= 100), a = full dot ----
    float xv0[8];
    #pragma unroll
    for (int i = 0; i < 8; ++i) xv0[i] = x0p[64 * i + lane];
    float yp[8], a[8];
    #pragma unroll
    for (int r = 0; r < 8; ++r){
        float sy = 0.f, st = 0.f;
        #pragma unroll
        for (int i = 0; i < 8; ++i){
            sy = fmaf(w2v[r][i], xv0[i], sy);
            st = fmaf(w1v[r][i], xv0[i], st);
        }
        yp[r] = sy; a[r] = st + sy;
    }
    #pragma unroll
    for (int off = 32; off >= 1; off >>= 1){
        #pragma unroll
        for (int r = 0; r < 8; ++r) a[r] += __shfl_xor(a[r], off, 64);
    }

    // ---- step 0 local; publish x_1 (tag 2) into ring slot 1 ----
    float xloc = 0.f, bval = 0.f;
    if (lane < 8){
        const int row = rowbase + lane;
        xloc = x0p[row];
        bval = bb[row];
        out[(size_t)row * (N + 1)] = xloc;
        if (N >= 1){
            const float x1 = xloc + dt * tanhf(sel8(a, lane) + bval);
            xloc = x1;
            ag_st(ring + D + row, pack_rec(2u, x1));
            out[(size_t)row * (N + 1) + 1] = x1;
        }
    }

    float* myh = hist + (size_t)wb * HSLOT * D;   // wave-private history

    u64 xr[8];
    float xf[8];
    int sx = 1, sp = 2, syr = 1;   // ring slots: j%M, (j+1)%M, (j-100)%M
    int hw = 0, hr = 0;            // history write/read slots
    bool dead = false;

    for (int j = 1; j < N && !dead; ++j){
        const bool needy  = (j > NTAU);
        const unsigned tx = (unsigned)(j + 1);
        const u64* px = ring + (size_t)sx * D + lane;

        // ---- fallback path only: agent y issued before the x-spin ----
        u64 yr[8];
        if (!use_hist && needy){
            const u64* py = ring + (size_t)syr * D + lane;
            #pragma unroll
            for (int i = 0; i < 8; ++i) yr[i] = ag_ld(py + 64 * i);
        }

        // ---- spin for x_j: 8 coalesced agent loads per lane ----
        int it = 0;
        for (;;){
            #pragma unroll
            for (int i = 0; i < 8; ++i) xr[i] = ag_ld(px + 64 * i);
            bool ok = true;
            #pragma unroll
            for (int i = 0; i < 8; ++i) ok &= ((unsigned)(xr[i] >> 32) == tx);
            if (__all(ok)) break;
            if (++it > (1 << 20)){ dead = true; break; }
        }
        #pragma unroll
        for (int i = 0; i < 8; ++i) xf[i] = lo_f(xr[i]);

        // ---- fallback path only: verify y, recompute yp on mismatch ----
        if (!use_hist && needy){
            const unsigned ty = (unsigned)(j - NTAU + 1);
            bool ok = true;
            #pragma unroll
            for (int i = 0; i < 8; ++i) ok &= ((unsigned)(yr[i] >> 32) == ty);
            if (!__all(ok)){
                const u64* py = ring + (size_t)syr * D + lane;
                int it2 = 0;
                for (;;){
                    #pragma unroll
                    for (int i = 0; i < 8; ++i) yr[i] = ag_ld(py + 64 * i);
                    bool ok2 = true;
                    #pragma unroll
                    for (int i = 0; i < 8; ++i) ok2 &= ((unsigned)(yr[i] >> 32) == ty);
                    if (__all(ok2)) break;
                    if (++it2 > (1 << 20)){ dead = true; break; }
                }
            }
            #pragma unroll
            for (int r = 0; r < 8; ++r){
                float sy = 0.f;
                #pragma unroll
                for (int i = 0; i < 8; ++i) sy = fmaf(w2v[r][i], lo_f(yr[i]), sy);
                yp[r] = sy;
            }
        }

        // ---- critical path: 64 FMAs + butterfly + integrate + publish ----
        #pragma unroll
        for (int r = 0; r < 8; ++r){
            float s = yp[r];
            #pragma unroll
            for (int i = 0; i < 8; ++i) s = fmaf(w1v[r][i], xf[i], s);
            a[r] = s;
        }
        #pragma unroll
        for (int off = 32; off >= 1; off >>= 1){
            #pragma unroll
            for (int r = 0; r < 8; ++r) a[r] += __shfl_xor(a[r], off, 64);
        }
        if (lane < 8){
            const float xn = xloc + dt * tanhf(sel8(a, lane) + bval);
            xloc = xn;
            const int row = rowbase + lane;
            ag_st(ring + (size_t)sp * D + row, pack_rec(tx + 1, xn));
            out[(size_t)row * (N + 1) + (j + 1)] = xn;
        }

        // ---- post-publish shadow: history write + next-step y partial ----
        if (use_hist){
            float* hwp = myh + (size_t)hw * D + lane;
            #pragma unroll
            for (int i = 0; i < 8; ++i) hwp[64 * i] = xf[i];   // plain stores
            if (j >= NTAU){            // next step j+1 needs y = x_{j-99}
                const float* hrp = myh + (size_t)hr * D + lane;
                float yv[8];
                #pragma unroll
                for (int i = 0; i < 8; ++i) yv[i] = hrp[64 * i];  // plain loads
                #pragma unroll
                for (int r = 0; r < 8; ++r){
                    float sy = 0.f;
                    #pragma unroll
                    for (int i = 0; i < 8; ++i) sy = fmaf(w2v[r][i], yv[i], sy);
                    yp[r] = sy;
                }
                hr = (hr == HSLOT - 1) ? 0 : hr + 1;
            }
            hw = (hw == HSLOT - 1) ? 0 : hw + 1;
        }

        sx = (sx == M - 1) ? 0 : sx + 1;
        sp = (sp == M - 1) ? 0 : sp + 1;
        if (j >= NTAU + 1) syr = (syr == M - 1) ? 0 : syr + 1;
    }
}

extern "C" void kernel_launch(void* const* d_in, const int* in_sizes, int n_in,
                              void* d_out, int out_size, void* d_ws, size_t ws_size,
                              hipStream_t stream)
{
    const float* x0  = (const float*)d_in[0];
    const float* tau = (const float*)d_in[1];
    const float* W1  = (const float*)d_in[2];
    const float* W2  = (const float*)d_in[3];
    const float* b   = (const float*)d_in[4];
    const int*   Np  = (const int*)  d_in[5];

    // d_ws layout: ring [0, M*D*8 = 458752); history after.
    const size_t ring_bytes = (size_t)M * D * 8;
    const size_t hist_bytes = (size_t)NW * HSLOT * D * 4;
    const int use_hist = (ws_size >= ring_bytes + hist_bytes) ? 1 : 0;

    u64*   ring = (u64*)d_ws;
    float* hist = (float*)((char*)d_ws + ring_bytes);

    hipLaunchKernelGGL(ndde_r5, dim3(NW), dim3(64), 0, stream,
                       x0, tau, W1, W2, b, Np, (float*)d_out, ring, hist, use_hist);
}